// Round 1
// baseline (455.269 us; speedup 1.0000x reference)
//
#include <hip/hip_runtime.h>

#define D 128
#define NSLOPE 0.2f
#define LN_EPS 1e-5f

__device__ __forceinline__ float leaky(float x) { return x > 0.f ? x : NSLOPE * x; }

// ---------------- CSR build ----------------
__global__ void k_deg(const int* __restrict__ ei, int* __restrict__ deg, int e) {
    int i = blockIdx.x * blockDim.x + threadIdx.x;
    if (i < e) atomicAdd(&deg[ei[e + i]], 1);   // dst row is second half
}

__global__ __launch_bounds__(1024) void k_scan(const int* __restrict__ deg,
                                               int* __restrict__ rowptr, int n) {
    __shared__ int lds[1024];
    int t = threadIdx.x;
    int chunk = (n + 1023) >> 10;
    int lo = t * chunk;
    int hi = min(lo + chunk, n);
    int s = 0;
    for (int i = lo; i < hi; ++i) s += deg[i];
    lds[t] = s;
    __syncthreads();
    for (int off = 1; off < 1024; off <<= 1) {
        int v = (t >= off) ? lds[t - off] : 0;
        __syncthreads();
        lds[t] += v;
        __syncthreads();
    }
    int base = lds[t] - s;   // exclusive prefix
    for (int i = lo; i < hi; ++i) { rowptr[i] = base; base += deg[i]; }
    if (t == 1023) rowptr[n] = lds[1023];
}

__global__ void k_fill(const int* __restrict__ ei, const int* __restrict__ rowptr,
                       int* __restrict__ cur, int* __restrict__ csr, int e) {
    int i = blockIdx.x * blockDim.x + threadIdx.x;
    if (i < e) {
        int d = ei[e + i];
        int p = atomicAdd(&cur[d], 1);
        csr[rowptr[d] + p] = ei[i];   // store src
    }
}

// ---------------- w_src = W @ att_src ; w_dst = W @ att_dst ----------------
__global__ void k_wvec(const float* __restrict__ W, const float* __restrict__ as,
                       const float* __restrict__ ad, float* __restrict__ wsrc,
                       float* __restrict__ wdst) {
    int d = threadIdx.x;          // 0..127
    const float* wr = W + d * D;
    float s0 = 0.f, s1 = 0.f;
    for (int k = 0; k < D; ++k) { float w = wr[k]; s0 += w * as[k]; s1 += w * ad[k]; }
    wsrc[d] = s0; wdst[d] = s1;
}

// ---------------- a_src[i] = x[i]·w_src ; a_dst[i] = x[i]·w_dst ----------------
__global__ __launch_bounds__(256) void k_a(const float* __restrict__ x,
        const float* __restrict__ wsrc, const float* __restrict__ wdst,
        float* __restrict__ asrc, float* __restrict__ adst, int n) {
    int node = blockIdx.x * 4 + (threadIdx.x >> 6);
    if (node >= n) return;
    int lane = threadIdx.x & 63;
    float2 xv = *(const float2*)&x[(size_t)node * D + lane * 2];
    float2 ws = *(const float2*)&wsrc[lane * 2];
    float2 wd = *(const float2*)&wdst[lane * 2];
    float s0 = xv.x * ws.x + xv.y * ws.y;
    float s1 = xv.x * wd.x + xv.y * wd.y;
    #pragma unroll
    for (int off = 32; off; off >>= 1) {
        s0 += __shfl_xor(s0, off);
        s1 += __shfl_xor(s1, off);
    }
    if (lane == 0) { asrc[node] = s0; adst[node] = s1; }
}

// ---------------- h = x @ W  (64 rows/block, f32, LDS-tiled) ----------------
__global__ __launch_bounds__(256) void k_gemm(const float* __restrict__ x,
        const float* __restrict__ W, float* __restrict__ h, int n) {
    __shared__ float Xs[64 * D];      // 32 KB
    __shared__ float Ws[32 * D];      // 16 KB (K-chunked)
    int t = threadIdx.x;
    int brow = blockIdx.x * 64;
    int rows = min(64, n - brow);

    // stage X tile
    const float4* X4 = (const float4*)(x + (size_t)brow * D);
    float4* Xs4 = (float4*)Xs;
    int nfl4 = rows * (D / 4);
    for (int i = t; i < nfl4; i += 256) Xs4[i] = X4[i];

    int cg = t & 31;        // col group: cols cg*4 .. cg*4+3
    int rg = t >> 5;        // row group: rows rg*8 .. rg*8+7
    float4 acc[8];
    #pragma unroll
    for (int i = 0; i < 8; ++i) acc[i] = make_float4(0.f, 0.f, 0.f, 0.f);

    float4* Ws4 = (float4*)Ws;
    for (int kc = 0; kc < D; kc += 32) {
        __syncthreads();
        const float4* Wc4 = (const float4*)(W + (size_t)kc * D);
        #pragma unroll
        for (int i = 0; i < 4; ++i) Ws4[t + 256 * i] = Wc4[t + 256 * i];
        __syncthreads();
        #pragma unroll
        for (int k4 = 0; k4 < 32; k4 += 4) {
            float4 xr[8];
            #pragma unroll
            for (int i = 0; i < 8; ++i)
                xr[i] = *(const float4*)&Xs[(rg * 8 + i) * D + kc + k4];
            #pragma unroll
            for (int kk = 0; kk < 4; ++kk) {
                float4 wv = *(const float4*)&Ws[(k4 + kk) * D + cg * 4];
                #pragma unroll
                for (int i = 0; i < 8; ++i) {
                    float xv = kk == 0 ? xr[i].x : kk == 1 ? xr[i].y : kk == 2 ? xr[i].z : xr[i].w;
                    acc[i].x += xv * wv.x;
                    acc[i].y += xv * wv.y;
                    acc[i].z += xv * wv.z;
                    acc[i].w += xv * wv.w;
                }
            }
        }
    }
    #pragma unroll
    for (int i = 0; i < 8; ++i) {
        int r = rg * 8 + i;
        if (r < rows) *(float4*)&h[(size_t)(brow + r) * D + cg * 4] = acc[i];
    }
}

// ---------------- fused: edge softmax + aggregate + residual + LayerNorm ----------------
__global__ __launch_bounds__(256) void k_attn(const float* __restrict__ x,
        const float* __restrict__ h, const float* __restrict__ asrc,
        const float* __restrict__ adst, const int* __restrict__ rowptr,
        const int* __restrict__ csr, const float* __restrict__ bias,
        const float* __restrict__ gamma, const float* __restrict__ beta,
        float* __restrict__ out, int n) {
    int node = blockIdx.x * 4 + (threadIdx.x >> 6);
    if (node >= n) return;
    int lane = threadIdx.x & 63;

    float a_i_dst = adst[node];
    float sl = leaky(asrc[node] + a_i_dst);   // self-loop logit
    int rs = rowptr[node], re = rowptr[node + 1];

    // pass 1: max logit (lanes parallel over edges)
    float m = sl;
    for (int e = rs + lane; e < re; e += 64) {
        float lg = leaky(asrc[csr[e]] + a_i_dst);
        m = fmaxf(m, lg);
    }
    #pragma unroll
    for (int off = 32; off; off >>= 1) m = fmaxf(m, __shfl_xor(m, off));

    // pass 2: serial over edges, vector over D (float2/lane)
    float2 acc = make_float2(0.f, 0.f);
    float ssum = 0.f;
    for (int e = rs; e < re; ++e) {
        int s = csr[e];                                    // uniform across wave
        float w = __expf(leaky(asrc[s] + a_i_dst) - m);    // uniform
        ssum += w;
        float2 hv = *(const float2*)&h[(size_t)s * D + lane * 2];
        acc.x += w * hv.x;
        acc.y += w * hv.y;
    }
    {   // self loop
        float w = __expf(sl - m);
        ssum += w;
        float2 hv = *(const float2*)&h[(size_t)node * D + lane * 2];
        acc.x += w * hv.x;
        acc.y += w * hv.y;
    }
    float inv = 1.f / ssum;

    float2 xv = *(const float2*)&x[(size_t)node * D + lane * 2];
    float2 bv = *(const float2*)&bias[lane * 2];
    float y0 = xv.x + acc.x * inv + bv.x;
    float y1 = xv.y + acc.y * inv + bv.y;

    // LayerNorm across 128 (2 per lane)
    float s1 = y0 + y1, s2 = y0 * y0 + y1 * y1;
    #pragma unroll
    for (int off = 32; off; off >>= 1) {
        s1 += __shfl_xor(s1, off);
        s2 += __shfl_xor(s2, off);
    }
    float mu = s1 * (1.f / D);
    float var = s2 * (1.f / D) - mu * mu;
    float rstd = rsqrtf(var + LN_EPS);
    float2 gv = *(const float2*)&gamma[lane * 2];
    float2 btv = *(const float2*)&beta[lane * 2];
    float o0 = (y0 - mu) * rstd * gv.x + btv.x;
    float o1 = (y1 - mu) * rstd * gv.y + btv.y;
    *(float2*)&out[(size_t)node * D + lane * 2] = make_float2(o0, o1);
}

extern "C" void kernel_launch(void* const* d_in, const int* in_sizes, int n_in,
                              void* d_out, int out_size, void* d_ws, size_t ws_size,
                              hipStream_t stream) {
    const float* x       = (const float*)d_in[0];
    const int*   ei      = (const int*)d_in[1];
    const float* W       = (const float*)d_in[2];
    const float* att_src = (const float*)d_in[3];
    const float* att_dst = (const float*)d_in[4];
    const float* bias    = (const float*)d_in[5];
    const float* gamma   = (const float*)d_in[6];
    const float* beta    = (const float*)d_in[7];
    float* out = (float*)d_out;

    const int N = in_sizes[0] / D;
    const int E = in_sizes[1] / 2;
    const int L = in_sizes[2] / (D * D);

    char* base = (char*)d_ws;
    size_t off = 0;
    auto alloc = [&](size_t bytes) {
        char* p = base + off;
        off += (bytes + 255) & ~(size_t)255;
        return p;
    };
    float* h      = (float*)alloc((size_t)N * D * 4);
    float* asrc   = (float*)alloc((size_t)N * 4);
    float* adst   = (float*)alloc((size_t)N * 4);
    float* wsrc   = (float*)alloc(D * 4);
    float* wdst   = (float*)alloc(D * 4);
    int*   deg    = (int*)alloc((size_t)N * 4);      // also reused as fill cursor
    int*   rowptr = (int*)alloc((size_t)(N + 1) * 4);
    int*   csr    = (int*)alloc((size_t)E * 4);

    // ---- CSR build (per call; cheap) ----
    hipMemsetAsync(deg, 0, (size_t)N * 4, stream);
    k_deg<<<(E + 255) / 256, 256, 0, stream>>>(ei, deg, E);
    k_scan<<<1, 1024, 0, stream>>>(deg, rowptr, N);
    hipMemsetAsync(deg, 0, (size_t)N * 4, stream);
    k_fill<<<(E + 255) / 256, 256, 0, stream>>>(ei, rowptr, deg, csr, E);

    const int nblk_node = (N + 3) / 4;
    for (int l = 0; l < L; ++l) {
        const float* xl = (l == 0) ? x : out;
        k_wvec<<<1, D, 0, stream>>>(W + (size_t)l * D * D, att_src + (size_t)l * D,
                                    att_dst + (size_t)l * D, wsrc, wdst);
        k_gemm<<<(N + 63) / 64, 256, 0, stream>>>(xl, W + (size_t)l * D * D, h, N);
        k_a<<<nblk_node, 256, 0, stream>>>(xl, wsrc, wdst, asrc, adst, N);
        k_attn<<<nblk_node, 256, 0, stream>>>(xl, h, asrc, adst, rowptr, csr,
                                              bias + (size_t)l * D, gamma + (size_t)l * D,
                                              beta + (size_t)l * D, out, N);
    }
}

// Round 2
// 340.168 us; speedup vs baseline: 1.3384x; 1.3384x over previous
//
#include <hip/hip_runtime.h>

#define D 128
#define NSLOPE 0.2f
#define LN_EPS 1e-5f

typedef unsigned int uint;

__device__ __forceinline__ float leaky(float x) { return x > 0.f ? x : NSLOPE * x; }
__device__ __forceinline__ float blo(uint u) { return __uint_as_float(u << 16); }
__device__ __forceinline__ float bhi(uint u) { return __uint_as_float(u & 0xffff0000u); }
__device__ __forceinline__ uint bpack(float a, float b) {
    uint ua = __float_as_uint(a), ub = __float_as_uint(b);
    ua = (ua + 0x7fffu + ((ua >> 16) & 1u)) >> 16;
    ub = (ub + 0x7fffu + ((ub >> 16) & 1u)) >> 16;
    return ua | (ub << 16);
}

// ---------------- CSR build ----------------
__global__ void k_deg(const int* __restrict__ ei, int* __restrict__ deg, int e) {
    int i = blockIdx.x * blockDim.x + threadIdx.x;
    if (i < e) atomicAdd(&deg[ei[e + i]], 1);
}

__global__ __launch_bounds__(1024) void k_scan(const int* __restrict__ deg,
                                               int* __restrict__ rowptr, int n) {
    __shared__ int lds[1024];
    int t = threadIdx.x;
    int chunk = (n + 1023) >> 10;
    int lo = t * chunk;
    int hi = min(lo + chunk, n);
    int s = 0;
    for (int i = lo; i < hi; ++i) s += deg[i];
    lds[t] = s;
    __syncthreads();
    for (int off = 1; off < 1024; off <<= 1) {
        int v = (t >= off) ? lds[t - off] : 0;
        __syncthreads();
        lds[t] += v;
        __syncthreads();
    }
    int base = lds[t] - s;
    for (int i = lo; i < hi; ++i) { rowptr[i] = base; base += deg[i]; }
    if (t == 1023) rowptr[n] = lds[1023];
}

__global__ void k_fill(const int* __restrict__ ei, const int* __restrict__ rowptr,
                       int* __restrict__ cur, int* __restrict__ csr, int e) {
    int i = blockIdx.x * blockDim.x + threadIdx.x;
    if (i < e) {
        int d = ei[e + i];
        int p = atomicAdd(&cur[d], 1);
        csr[rowptr[d] + p] = ei[i];
    }
}

// ---------------- h = x @ W (bf16 out) + fused a_src/a_dst epilogue ----------------
__global__ __launch_bounds__(256) void k_gemm(const float* __restrict__ x,
        const float* __restrict__ W, const float* __restrict__ avs,
        const float* __restrict__ avd, uint* __restrict__ hb,
        float* __restrict__ asrc, float* __restrict__ adst, int n) {
    __shared__ float Xs[64 * D];      // 32 KB
    __shared__ float Ws[32 * D];      // 16 KB (K-chunked)
    int t = threadIdx.x;
    int brow = blockIdx.x * 64;
    int rows = min(64, n - brow);

    const float4* X4 = (const float4*)(x + (size_t)brow * D);
    float4* Xs4 = (float4*)Xs;
    int nfl4 = rows * (D / 4);
    for (int i = t; i < nfl4; i += 256) Xs4[i] = X4[i];

    int cg = t & 31;        // cols cg*4 .. cg*4+3
    int rg = t >> 5;        // rows rg*8 .. rg*8+7
    float4 acc[8];
    #pragma unroll
    for (int i = 0; i < 8; ++i) acc[i] = make_float4(0.f, 0.f, 0.f, 0.f);

    float4* Ws4 = (float4*)Ws;
    for (int kc = 0; kc < D; kc += 32) {
        __syncthreads();
        const float4* Wc4 = (const float4*)(W + (size_t)kc * D);
        #pragma unroll
        for (int i = 0; i < 4; ++i) Ws4[t + 256 * i] = Wc4[t + 256 * i];
        __syncthreads();
        #pragma unroll
        for (int k4 = 0; k4 < 32; k4 += 4) {
            float4 xr[8];
            #pragma unroll
            for (int i = 0; i < 8; ++i)
                xr[i] = *(const float4*)&Xs[(rg * 8 + i) * D + kc + k4];
            #pragma unroll
            for (int kk = 0; kk < 4; ++kk) {
                float4 wv = *(const float4*)&Ws[(k4 + kk) * D + cg * 4];
                #pragma unroll
                for (int i = 0; i < 8; ++i) {
                    float xv = kk == 0 ? xr[i].x : kk == 1 ? xr[i].y : kk == 2 ? xr[i].z : xr[i].w;
                    acc[i].x += xv * wv.x;
                    acc[i].y += xv * wv.y;
                    acc[i].z += xv * wv.z;
                    acc[i].w += xv * wv.w;
                }
            }
        }
    }

    // fused epilogue: a_src/a_dst partial dots over this thread's 4 cols
    float4 av_s = *(const float4*)&avs[cg * 4];
    float4 av_d = *(const float4*)&avd[cg * 4];
    #pragma unroll
    for (int i = 0; i < 8; ++i) {
        float ps = acc[i].x * av_s.x + acc[i].y * av_s.y + acc[i].z * av_s.z + acc[i].w * av_s.w;
        float pd = acc[i].x * av_d.x + acc[i].y * av_d.y + acc[i].z * av_d.z + acc[i].w * av_d.w;
        #pragma unroll
        for (int off = 16; off; off >>= 1) {
            ps += __shfl_xor(ps, off);
            pd += __shfl_xor(pd, off);
        }
        int r = rg * 8 + i;
        if (cg == 0 && r < rows) {
            asrc[brow + r] = ps;
            adst[brow + r] = pd;
        }
    }
    // bf16 h store: row stride 64 uints; uint j holds channels {2j, 2j+1}
    #pragma unroll
    for (int i = 0; i < 8; ++i) {
        int r = rg * 8 + i;
        if (r < rows) {
            uint2 w = make_uint2(bpack(acc[i].x, acc[i].y), bpack(acc[i].z, acc[i].w));
            *(uint2*)&hb[(size_t)(brow + r) * 64 + cg * 2] = w;
        }
    }
}

// ---------------- fused: edge softmax + aggregate (bf16 gather, 4 edges/wave) + LN ----------------
__global__ __launch_bounds__(256) void k_attn(const float* __restrict__ x,
        const uint* __restrict__ hb, const float* __restrict__ asrc,
        const float* __restrict__ adst, const int* __restrict__ rowptr,
        const int* __restrict__ csr, const float* __restrict__ bias,
        const float* __restrict__ gamma, const float* __restrict__ beta,
        float* __restrict__ out, int n) {
    int node = blockIdx.x * 4 + (threadIdx.x >> 6);
    if (node >= n) return;
    int lane = threadIdx.x & 63;
    int grp = lane >> 4;          // 4 edge-groups
    int sl = lane & 15;           // sublane: channels sl*8 .. sl*8+7

    float a_i = adst[node];
    float slg = leaky(asrc[node] + a_i);   // self-loop logit
    int rs = rowptr[node], re = rowptr[node + 1];

    // pass 1: max logit, lanes parallel over edges
    float m = slg;
    for (int e = rs + lane; e < re; e += 64)
        m = fmaxf(m, leaky(asrc[csr[e]] + a_i));
    #pragma unroll
    for (int off = 32; off; off >>= 1) m = fmaxf(m, __shfl_xor(m, off));

    // pass 2: 4 edges in parallel (one per 16-lane group), 8 channels/lane
    float acc[8] = {0.f, 0.f, 0.f, 0.f, 0.f, 0.f, 0.f, 0.f};
    float ssum = 0.f;
    for (int e = rs; e < re; e += 4) {
        int ee = e + grp;
        if (ee < re) {
            int s = csr[ee];
            float w = __expf(leaky(asrc[s] + a_i) - m);
            ssum += w;
            uint4 q = *(const uint4*)&hb[(size_t)s * 64 + sl * 4];
            acc[0] += w * blo(q.x); acc[1] += w * bhi(q.x);
            acc[2] += w * blo(q.y); acc[3] += w * bhi(q.y);
            acc[4] += w * blo(q.z); acc[5] += w * bhi(q.z);
            acc[6] += w * blo(q.w); acc[7] += w * bhi(q.w);
        }
    }
    if (grp == 0) {  // self loop, group 0 only (groups are summed below)
        float w = __expf(slg - m);
        ssum += w;
        uint4 q = *(const uint4*)&hb[(size_t)node * 64 + sl * 4];
        acc[0] += w * blo(q.x); acc[1] += w * bhi(q.x);
        acc[2] += w * blo(q.y); acc[3] += w * bhi(q.y);
        acc[4] += w * blo(q.z); acc[5] += w * bhi(q.z);
        acc[6] += w * blo(q.w); acc[7] += w * bhi(q.w);
    }
    // reduce across the 4 groups (lanes with same sublane)
    #pragma unroll
    for (int off = 16; off <= 32; off <<= 1) {
        ssum += __shfl_xor(ssum, off);
        #pragma unroll
        for (int j = 0; j < 8; ++j) acc[j] += __shfl_xor(acc[j], off);
    }
    float inv = 1.f / ssum;

    // residual + LayerNorm (8 channels per lane, groups hold identical copies)
    float4 xa = *(const float4*)&x[(size_t)node * D + sl * 8];
    float4 xb = *(const float4*)&x[(size_t)node * D + sl * 8 + 4];
    float4 ba = *(const float4*)&bias[sl * 8];
    float4 bb = *(const float4*)&bias[sl * 8 + 4];
    float y[8];
    y[0] = xa.x + acc[0] * inv + ba.x;
    y[1] = xa.y + acc[1] * inv + ba.y;
    y[2] = xa.z + acc[2] * inv + ba.z;
    y[3] = xa.w + acc[3] * inv + ba.w;
    y[4] = xb.x + acc[4] * inv + bb.x;
    y[5] = xb.y + acc[5] * inv + bb.y;
    y[6] = xb.z + acc[6] * inv + bb.z;
    y[7] = xb.w + acc[7] * inv + bb.w;

    float s1 = 0.f, s2 = 0.f;
    #pragma unroll
    for (int j = 0; j < 8; ++j) { s1 += y[j]; s2 += y[j] * y[j]; }
    #pragma unroll
    for (int off = 1; off <= 8; off <<= 1) {
        s1 += __shfl_xor(s1, off);
        s2 += __shfl_xor(s2, off);
    }
    float mu = s1 * (1.f / D);
    float var = s2 * (1.f / D) - mu * mu;
    float rstd = rsqrtf(var + LN_EPS);

    if (grp == 0) {
        float4 ga = *(const float4*)&gamma[sl * 8];
        float4 gb = *(const float4*)&gamma[sl * 8 + 4];
        float4 bta = *(const float4*)&beta[sl * 8];
        float4 btb = *(const float4*)&beta[sl * 8 + 4];
        float4 o0, o1;
        o0.x = (y[0] - mu) * rstd * ga.x + bta.x;
        o0.y = (y[1] - mu) * rstd * ga.y + bta.y;
        o0.z = (y[2] - mu) * rstd * ga.z + bta.z;
        o0.w = (y[3] - mu) * rstd * ga.w + bta.w;
        o1.x = (y[4] - mu) * rstd * gb.x + btb.x;
        o1.y = (y[5] - mu) * rstd * gb.y + btb.y;
        o1.z = (y[6] - mu) * rstd * gb.z + btb.z;
        o1.w = (y[7] - mu) * rstd * gb.w + btb.w;
        *(float4*)&out[(size_t)node * D + sl * 8] = o0;
        *(float4*)&out[(size_t)node * D + sl * 8 + 4] = o1;
    }
}

extern "C" void kernel_launch(void* const* d_in, const int* in_sizes, int n_in,
                              void* d_out, int out_size, void* d_ws, size_t ws_size,
                              hipStream_t stream) {
    const float* x       = (const float*)d_in[0];
    const int*   ei      = (const int*)d_in[1];
    const float* W       = (const float*)d_in[2];
    const float* att_src = (const float*)d_in[3];
    const float* att_dst = (const float*)d_in[4];
    const float* bias    = (const float*)d_in[5];
    const float* gamma   = (const float*)d_in[6];
    const float* beta    = (const float*)d_in[7];
    float* out = (float*)d_out;

    const int N = in_sizes[0] / D;
    const int E = in_sizes[1] / 2;
    const int L = in_sizes[2] / (D * D);

    char* base = (char*)d_ws;
    size_t off = 0;
    auto alloc = [&](size_t bytes) {
        char* p = base + off;
        off += (bytes + 255) & ~(size_t)255;
        return p;
    };
    uint*  hb     = (uint*)alloc((size_t)N * 64 * 4);   // bf16-packed h
    float* asrc   = (float*)alloc((size_t)N * 4);
    float* adst   = (float*)alloc((size_t)N * 4);
    int*   deg    = (int*)alloc((size_t)N * 4);
    int*   rowptr = (int*)alloc((size_t)(N + 1) * 4);
    int*   csr    = (int*)alloc((size_t)E * 4);

    hipMemsetAsync(deg, 0, (size_t)N * 4, stream);
    k_deg<<<(E + 255) / 256, 256, 0, stream>>>(ei, deg, E);
    k_scan<<<1, 1024, 0, stream>>>(deg, rowptr, N);
    hipMemsetAsync(deg, 0, (size_t)N * 4, stream);
    k_fill<<<(E + 255) / 256, 256, 0, stream>>>(ei, rowptr, deg, csr, E);

    const int nblk_node = (N + 3) / 4;
    for (int l = 0; l < L; ++l) {
        const float* xl = (l == 0) ? x : out;
        k_gemm<<<(N + 63) / 64, 256, 0, stream>>>(xl, W + (size_t)l * D * D,
                                                  att_src + (size_t)l * D,
                                                  att_dst + (size_t)l * D,
                                                  hb, asrc, adst, N);
        k_attn<<<nblk_node, 256, 0, stream>>>(xl, hb, asrc, adst, rowptr, csr,
                                              bias + (size_t)l * D, gamma + (size_t)l * D,
                                              beta + (size_t)l * D, out, N);
    }
}

// Round 3
// 273.526 us; speedup vs baseline: 1.6644x; 1.2436x over previous
//
#include <hip/hip_runtime.h>

#define D 128
#define NSLOPE 0.2f
#define LN_EPS 1e-5f

typedef unsigned int uint;

__device__ __forceinline__ float leaky(float x) { return x > 0.f ? x : NSLOPE * x; }
__device__ __forceinline__ float blo(uint u) { return __uint_as_float(u << 16); }
__device__ __forceinline__ float bhi(uint u) { return __uint_as_float(u & 0xffff0000u); }
__device__ __forceinline__ uint bpack(float a, float b) {
    uint ua = __float_as_uint(a), ub = __float_as_uint(b);
    ua = (ua + 0x7fffu + ((ua >> 16) & 1u)) >> 16;
    ub = (ub + 0x7fffu + ((ub >> 16) & 1u)) >> 16;
    return ua | (ub << 16);
}

// ---------------- CSR build ----------------
__global__ void k_deg(const int* __restrict__ ei, int* __restrict__ deg, int e) {
    int i = blockIdx.x * blockDim.x + threadIdx.x;
    if (i < e) atomicAdd(&deg[ei[e + i]], 1);
}

// two-level scan: block sums -> scan sums -> per-block rescan
__global__ __launch_bounds__(256) void k_bsum(const int* __restrict__ deg,
                                              int* __restrict__ bsum, int n) {
    int b = blockIdx.x, t = threadIdx.x;
    int base = b * 1024;
    int s = 0;
    #pragma unroll
    for (int i = 0; i < 4; ++i) {
        int idx = base + t + 256 * i;
        if (idx < n) s += deg[idx];
    }
    #pragma unroll
    for (int off = 32; off; off >>= 1) s += __shfl_xor(s, off);
    __shared__ int ws[4];
    if ((t & 63) == 0) ws[t >> 6] = s;
    __syncthreads();
    if (t == 0) bsum[b] = ws[0] + ws[1] + ws[2] + ws[3];
}

__global__ __launch_bounds__(256) void k_scanb(const int* __restrict__ bsum,
        int* __restrict__ ebsum, int* __restrict__ rowptr_n, int nb) {
    __shared__ int lds[256];
    int t = threadIdx.x;
    int v = (t < nb) ? bsum[t] : 0;
    lds[t] = v;
    __syncthreads();
    for (int off = 1; off < 256; off <<= 1) {
        int u = (t >= off) ? lds[t - off] : 0;
        __syncthreads();
        lds[t] += u;
        __syncthreads();
    }
    if (t < nb) ebsum[t] = lds[t] - v;
    if (t == 255) *rowptr_n = lds[255];
}

__global__ __launch_bounds__(256) void k_rowptr(const int* __restrict__ deg,
        const int* __restrict__ ebsum, int* __restrict__ rowptr, int n) {
    int b = blockIdx.x, t = threadIdx.x;
    int base = b * 1024 + t * 4;
    int d[4];
    #pragma unroll
    for (int j = 0; j < 4; ++j) d[j] = (base + j < n) ? deg[base + j] : 0;
    int s = d[0] + d[1] + d[2] + d[3];
    __shared__ int lds[256];
    lds[t] = s;
    __syncthreads();
    for (int off = 1; off < 256; off <<= 1) {
        int u = (t >= off) ? lds[t - off] : 0;
        __syncthreads();
        lds[t] += u;
        __syncthreads();
    }
    int pre = ebsum[b] + lds[t] - s;
    #pragma unroll
    for (int j = 0; j < 4; ++j) {
        if (base + j < n) { rowptr[base + j] = pre; pre += d[j]; }
    }
}

__global__ void k_fill(const int* __restrict__ ei, const int* __restrict__ rowptr,
                       int* __restrict__ cur, int* __restrict__ csr, int e) {
    int i = blockIdx.x * blockDim.x + threadIdx.x;
    if (i < e) {
        int d = ei[e + i];
        int p = atomicAdd(&cur[d], 1);
        csr[rowptr[d] + p] = ei[i];
    }
}

// ---------------- h = x @ W (bf16 out) + fused a_src/a_dst epilogue ----------------
__global__ __launch_bounds__(256) void k_gemm(const float* __restrict__ x,
        const float* __restrict__ W, const float* __restrict__ avs,
        const float* __restrict__ avd, uint* __restrict__ hb,
        float* __restrict__ asrc, float* __restrict__ adst, int n) {
    __shared__ float Xs[64 * D];      // 32 KB
    __shared__ float Ws[32 * D];      // 16 KB (K-chunked)
    int t = threadIdx.x;
    int brow = blockIdx.x * 64;
    int rows = min(64, n - brow);

    const float4* X4 = (const float4*)(x + (size_t)brow * D);
    float4* Xs4 = (float4*)Xs;
    int nfl4 = rows * (D / 4);
    for (int i = t; i < nfl4; i += 256) Xs4[i] = X4[i];

    int cg = t & 31;        // cols cg*4 .. cg*4+3
    int rg = t >> 5;        // rows rg*8 .. rg*8+7
    float4 acc[8];
    #pragma unroll
    for (int i = 0; i < 8; ++i) acc[i] = make_float4(0.f, 0.f, 0.f, 0.f);

    float4* Ws4 = (float4*)Ws;
    for (int kc = 0; kc < D; kc += 32) {
        __syncthreads();
        const float4* Wc4 = (const float4*)(W + (size_t)kc * D);
        #pragma unroll
        for (int i = 0; i < 4; ++i) Ws4[t + 256 * i] = Wc4[t + 256 * i];
        __syncthreads();
        #pragma unroll
        for (int k4 = 0; k4 < 32; k4 += 4) {
            float4 xr[8];
            #pragma unroll
            for (int i = 0; i < 8; ++i)
                xr[i] = *(const float4*)&Xs[(rg * 8 + i) * D + kc + k4];
            #pragma unroll
            for (int kk = 0; kk < 4; ++kk) {
                float4 wv = *(const float4*)&Ws[(k4 + kk) * D + cg * 4];
                #pragma unroll
                for (int i = 0; i < 8; ++i) {
                    float xv = kk == 0 ? xr[i].x : kk == 1 ? xr[i].y : kk == 2 ? xr[i].z : xr[i].w;
                    acc[i].x += xv * wv.x;
                    acc[i].y += xv * wv.y;
                    acc[i].z += xv * wv.z;
                    acc[i].w += xv * wv.w;
                }
            }
        }
    }

    // fused epilogue: a_src/a_dst partial dots over this thread's 4 cols
    float4 av_s = *(const float4*)&avs[cg * 4];
    float4 av_d = *(const float4*)&avd[cg * 4];
    #pragma unroll
    for (int i = 0; i < 8; ++i) {
        float ps = acc[i].x * av_s.x + acc[i].y * av_s.y + acc[i].z * av_s.z + acc[i].w * av_s.w;
        float pd = acc[i].x * av_d.x + acc[i].y * av_d.y + acc[i].z * av_d.z + acc[i].w * av_d.w;
        #pragma unroll
        for (int off = 16; off; off >>= 1) {
            ps += __shfl_xor(ps, off);
            pd += __shfl_xor(pd, off);
        }
        int r = rg * 8 + i;
        if (cg == 0 && r < rows) {
            asrc[brow + r] = ps;
            adst[brow + r] = pd;
        }
    }
    // bf16 h store: row stride 64 uints; uint j holds channels {2j, 2j+1}
    #pragma unroll
    for (int i = 0; i < 8; ++i) {
        int r = rg * 8 + i;
        if (r < rows) {
            uint2 w = make_uint2(bpack(acc[i].x, acc[i].y), bpack(acc[i].z, acc[i].w));
            *(uint2*)&hb[(size_t)(brow + r) * 64 + cg * 2] = w;
        }
    }
}

// ---------------- fused: edge softmax + aggregate (bf16 gather, 4 edges/wave) + LN ----------------
__global__ __launch_bounds__(256) void k_attn(const float* __restrict__ x,
        const uint* __restrict__ hb, const float* __restrict__ asrc,
        const float* __restrict__ adst, const int* __restrict__ rowptr,
        const int* __restrict__ csr, const float* __restrict__ bias,
        const float* __restrict__ gamma, const float* __restrict__ beta,
        float* __restrict__ out, int n) {
    int node = blockIdx.x * 4 + (threadIdx.x >> 6);
    if (node >= n) return;
    int lane = threadIdx.x & 63;
    int grp = lane >> 4;          // 4 edge-groups
    int sl = lane & 15;           // sublane: channels sl*8 .. sl*8+7

    float a_i = adst[node];
    float slg = leaky(asrc[node] + a_i);   // self-loop logit
    int rs = rowptr[node], re = rowptr[node + 1];

    // pass 1: max logit, lanes parallel over edges
    float m = slg;
    for (int e = rs + lane; e < re; e += 64)
        m = fmaxf(m, leaky(asrc[csr[e]] + a_i));
    #pragma unroll
    for (int off = 32; off; off >>= 1) m = fmaxf(m, __shfl_xor(m, off));

    // pass 2: 4 edges in parallel (one per 16-lane group), 8 channels/lane
    float acc[8] = {0.f, 0.f, 0.f, 0.f, 0.f, 0.f, 0.f, 0.f};
    float ssum = 0.f;
    for (int e = rs; e < re; e += 4) {
        int ee = e + grp;
        if (ee < re) {
            int s = csr[ee];
            float w = __expf(leaky(asrc[s] + a_i) - m);
            ssum += w;
            uint4 q = *(const uint4*)&hb[(size_t)s * 64 + sl * 4];
            acc[0] += w * blo(q.x); acc[1] += w * bhi(q.x);
            acc[2] += w * blo(q.y); acc[3] += w * bhi(q.y);
            acc[4] += w * blo(q.z); acc[5] += w * bhi(q.z);
            acc[6] += w * blo(q.w); acc[7] += w * bhi(q.w);
        }
    }
    if (grp == 0) {  // self loop
        float w = __expf(slg - m);
        ssum += w;
        uint4 q = *(const uint4*)&hb[(size_t)node * 64 + sl * 4];
        acc[0] += w * blo(q.x); acc[1] += w * bhi(q.x);
        acc[2] += w * blo(q.y); acc[3] += w * bhi(q.y);
        acc[4] += w * blo(q.z); acc[5] += w * bhi(q.z);
        acc[6] += w * blo(q.w); acc[7] += w * bhi(q.w);
    }
    // reduce across the 4 groups (lanes with same sublane)
    #pragma unroll
    for (int off = 16; off <= 32; off <<= 1) {
        ssum += __shfl_xor(ssum, off);
        #pragma unroll
        for (int j = 0; j < 8; ++j) acc[j] += __shfl_xor(acc[j], off);
    }
    float inv = 1.f / ssum;

    // residual + LayerNorm (8 channels per lane, groups hold identical copies)
    float4 xa = *(const float4*)&x[(size_t)node * D + sl * 8];
    float4 xb = *(const float4*)&x[(size_t)node * D + sl * 8 + 4];
    float4 ba = *(const float4*)&bias[sl * 8];
    float4 bb = *(const float4*)&bias[sl * 8 + 4];
    float y[8];
    y[0] = xa.x + acc[0] * inv + ba.x;
    y[1] = xa.y + acc[1] * inv + ba.y;
    y[2] = xa.z + acc[2] * inv + ba.z;
    y[3] = xa.w + acc[3] * inv + ba.w;
    y[4] = xb.x + acc[4] * inv + bb.x;
    y[5] = xb.y + acc[5] * inv + bb.y;
    y[6] = xb.z + acc[6] * inv + bb.z;
    y[7] = xb.w + acc[7] * inv + bb.w;

    float s1 = 0.f, s2 = 0.f;
    #pragma unroll
    for (int j = 0; j < 8; ++j) { s1 += y[j]; s2 += y[j] * y[j]; }
    #pragma unroll
    for (int off = 1; off <= 8; off <<= 1) {
        s1 += __shfl_xor(s1, off);
        s2 += __shfl_xor(s2, off);
    }
    float mu = s1 * (1.f / D);
    float var = s2 * (1.f / D) - mu * mu;
    float rstd = rsqrtf(var + LN_EPS);

    if (grp == 0) {
        float4 ga = *(const float4*)&gamma[sl * 8];
        float4 gb = *(const float4*)&gamma[sl * 8 + 4];
        float4 bta = *(const float4*)&beta[sl * 8];
        float4 btb = *(const float4*)&beta[sl * 8 + 4];
        float4 o0, o1;
        o0.x = (y[0] - mu) * rstd * ga.x + bta.x;
        o0.y = (y[1] - mu) * rstd * ga.y + bta.y;
        o0.z = (y[2] - mu) * rstd * ga.z + bta.z;
        o0.w = (y[3] - mu) * rstd * ga.w + bta.w;
        o1.x = (y[4] - mu) * rstd * gb.x + btb.x;
        o1.y = (y[5] - mu) * rstd * gb.y + btb.y;
        o1.z = (y[6] - mu) * rstd * gb.z + btb.z;
        o1.w = (y[7] - mu) * rstd * gb.w + btb.w;
        *(float4*)&out[(size_t)node * D + sl * 8] = o0;
        *(float4*)&out[(size_t)node * D + sl * 8 + 4] = o1;
    }
}

extern "C" void kernel_launch(void* const* d_in, const int* in_sizes, int n_in,
                              void* d_out, int out_size, void* d_ws, size_t ws_size,
                              hipStream_t stream) {
    const float* x       = (const float*)d_in[0];
    const int*   ei      = (const int*)d_in[1];
    const float* W       = (const float*)d_in[2];
    const float* att_src = (const float*)d_in[3];
    const float* att_dst = (const float*)d_in[4];
    const float* bias    = (const float*)d_in[5];
    const float* gamma   = (const float*)d_in[6];
    const float* beta    = (const float*)d_in[7];
    float* out = (float*)d_out;

    const int N = in_sizes[0] / D;
    const int E = in_sizes[1] / 2;
    const int L = in_sizes[2] / (D * D);

    char* base = (char*)d_ws;
    size_t off = 0;
    auto alloc = [&](size_t bytes) {
        char* p = base + off;
        off += (bytes + 255) & ~(size_t)255;
        return p;
    };
    uint*  hb     = (uint*)alloc((size_t)N * 64 * 4);   // bf16-packed h
    float* asrc   = (float*)alloc((size_t)N * 4);
    float* adst   = (float*)alloc((size_t)N * 4);
    int*   deg    = (int*)alloc((size_t)N * 4);
    int*   rowptr = (int*)alloc((size_t)(N + 1) * 4);
    int*   csr    = (int*)alloc((size_t)E * 4);
    const int nb  = (N + 1023) / 1024;                   // <= 256 for N <= 262144
    int*   bsum   = (int*)alloc((size_t)nb * 4);
    int*   ebsum  = (int*)alloc((size_t)nb * 4);

    hipMemsetAsync(deg, 0, (size_t)N * 4, stream);
    k_deg<<<(E + 255) / 256, 256, 0, stream>>>(ei, deg, E);
    k_bsum<<<nb, 256, 0, stream>>>(deg, bsum, N);
    k_scanb<<<1, 256, 0, stream>>>(bsum, ebsum, rowptr + N, nb);
    k_rowptr<<<nb, 256, 0, stream>>>(deg, ebsum, rowptr, N);
    hipMemsetAsync(deg, 0, (size_t)N * 4, stream);
    k_fill<<<(E + 255) / 256, 256, 0, stream>>>(ei, rowptr, deg, csr, E);

    const int nblk_node = (N + 3) / 4;
    for (int l = 0; l < L; ++l) {
        const float* xl = (l == 0) ? x : out;
        k_gemm<<<(N + 63) / 64, 256, 0, stream>>>(xl, W + (size_t)l * D * D,
                                                  att_src + (size_t)l * D,
                                                  att_dst + (size_t)l * D,
                                                  hb, asrc, adst, N);
        k_attn<<<nblk_node, 256, 0, stream>>>(xl, hb, asrc, adst, rowptr, csr,
                                              bias + (size_t)l * D, gamma + (size_t)l * D,
                                              beta + (size_t)l * D, out, N);
    }
}

// Round 4
// 215.998 us; speedup vs baseline: 2.1077x; 1.2663x over previous
//
#include <hip/hip_runtime.h>

#define D 128
#define NSLOPE 0.2f
#define LN_EPS 1e-5f

typedef unsigned int uint;
typedef float f32x4 __attribute__((ext_vector_type(4)));
typedef short s16x8 __attribute__((ext_vector_type(8)));

__device__ __forceinline__ float leaky(float x) { return x > 0.f ? x : NSLOPE * x; }
__device__ __forceinline__ float blo(uint u) { return __uint_as_float(u << 16); }
__device__ __forceinline__ float bhi(uint u) { return __uint_as_float(u & 0xffff0000u); }
__device__ __forceinline__ uint rne16(float v) {
    uint u = __float_as_uint(v);
    return (u + 0x7fffu + ((u >> 16) & 1u)) >> 16;
}
__device__ __forceinline__ float fromtop(uint hw) { return __uint_as_float(hw << 16); }
__device__ __forceinline__ uint bpack(float a, float b) { return rne16(a) | (rne16(b) << 16); }

// ---------------- CSR build ----------------
// degree + per-edge rank in one pass (rank removes the atomic pass from fill)
__global__ void k_degrank(const int* __restrict__ ei, int* __restrict__ deg,
                          int* __restrict__ rank, int e) {
    int i = blockIdx.x * blockDim.x + threadIdx.x;
    if (i < e) rank[i] = atomicAdd(&deg[ei[e + i]], 1);
}

__global__ __launch_bounds__(256) void k_bsum(const int* __restrict__ deg,
                                              int* __restrict__ bsum, int n) {
    int b = blockIdx.x, t = threadIdx.x;
    int base = b * 1024;
    int s = 0;
    #pragma unroll
    for (int i = 0; i < 4; ++i) {
        int idx = base + t + 256 * i;
        if (idx < n) s += deg[idx];
    }
    #pragma unroll
    for (int off = 32; off; off >>= 1) s += __shfl_xor(s, off);
    __shared__ int ws[4];
    if ((t & 63) == 0) ws[t >> 6] = s;
    __syncthreads();
    if (t == 0) bsum[b] = ws[0] + ws[1] + ws[2] + ws[3];
}

__global__ __launch_bounds__(256) void k_scanb(const int* __restrict__ bsum,
        int* __restrict__ ebsum, int* __restrict__ rowptr_n, int nb) {
    __shared__ int lds[256];
    int t = threadIdx.x;
    int v = (t < nb) ? bsum[t] : 0;
    lds[t] = v;
    __syncthreads();
    for (int off = 1; off < 256; off <<= 1) {
        int u = (t >= off) ? lds[t - off] : 0;
        __syncthreads();
        lds[t] += u;
        __syncthreads();
    }
    if (t < nb) ebsum[t] = lds[t] - v;
    if (t == 255) *rowptr_n = lds[255];
}

__global__ __launch_bounds__(256) void k_rowptr(const int* __restrict__ deg,
        const int* __restrict__ ebsum, int* __restrict__ rowptr, int n) {
    int b = blockIdx.x, t = threadIdx.x;
    int base = b * 1024 + t * 4;
    int d[4];
    #pragma unroll
    for (int j = 0; j < 4; ++j) d[j] = (base + j < n) ? deg[base + j] : 0;
    int s = d[0] + d[1] + d[2] + d[3];
    __shared__ int lds[256];
    lds[t] = s;
    __syncthreads();
    for (int off = 1; off < 256; off <<= 1) {
        int u = (t >= off) ? lds[t - off] : 0;
        __syncthreads();
        lds[t] += u;
        __syncthreads();
    }
    int pre = ebsum[b] + lds[t] - s;
    #pragma unroll
    for (int j = 0; j < 4; ++j) {
        if (base + j < n) { rowptr[base + j] = pre; pre += d[j]; }
    }
}

__global__ void k_fill2(const int* __restrict__ ei, const int* __restrict__ rowptr,
                        const int* __restrict__ rank, int* __restrict__ csr, int e) {
    int i = blockIdx.x * blockDim.x + threadIdx.x;
    if (i < e) csr[rowptr[ei[e + i]] + rank[i]] = ei[i];
}

// ---------------- W transpose + bf16 hi/lo split: Wt[c][k] ----------------
// wthi/wtlo: [128 cols][64 uints]; uint j packs k=2j (lo16) and k=2j+1 (hi16)
__global__ __launch_bounds__(256) void k_wt(const float* __restrict__ W,
                                            uint* __restrict__ wthi,
                                            uint* __restrict__ wtlo) {
    __shared__ float T[128][17];
    int t = threadIdx.x;
    int c0 = blockIdx.x * 16;
    #pragma unroll
    for (int pass = 0; pass < 2; ++pass) {
        int k = pass * 64 + (t >> 2);
        int c = (t & 3) * 4;
        float4 v = *(const float4*)&W[k * D + c0 + c];
        T[k][c] = v.x; T[k][c + 1] = v.y; T[k][c + 2] = v.z; T[k][c + 3] = v.w;
    }
    __syncthreads();
    int cw = t >> 4;          // 0..15
    int k0 = (t & 15) * 8;    // 8 consecutive k
    float v[8], lo[8];
    uint h[8];
    #pragma unroll
    for (int j = 0; j < 8; ++j) {
        v[j] = T[k0 + j][cw];
        h[j] = rne16(v[j]);
        lo[j] = v[j] - fromtop(h[j]);
    }
    uint4 uh, ul;
    uh.x = h[0] | (h[1] << 16); uh.y = h[2] | (h[3] << 16);
    uh.z = h[4] | (h[5] << 16); uh.w = h[6] | (h[7] << 16);
    ul.x = bpack(lo[0], lo[1]); ul.y = bpack(lo[2], lo[3]);
    ul.z = bpack(lo[4], lo[5]); ul.w = bpack(lo[6], lo[7]);
    *(uint4*)&wthi[(c0 + cw) * 64 + (t & 15) * 4] = uh;
    *(uint4*)&wtlo[(c0 + cw) * 64 + (t & 15) * 4] = ul;
}

// ---------------- MFMA gemm: h = x@W (3-pass split bf16), fused a_src/a_dst ----------------
// hb layout: row r, uint u (0..63): u = wave*16 + c15 packs cols (wave*32+c15, wave*32+c15+16)
__global__ __launch_bounds__(256) void k_gemm2(const float* __restrict__ x,
        const uint* __restrict__ wthi, const uint* __restrict__ wtlo,
        const float* __restrict__ avs, const float* __restrict__ avd,
        uint* __restrict__ hb, float* __restrict__ asrc, float* __restrict__ adst, int n) {
    __shared__ char XH[64 * 256];   // [row][k] bf16, swizzled
    __shared__ char XL[64 * 256];
    __shared__ char WH[128 * 128];  // [col][64k chunk] bf16, swizzled
    __shared__ char WL[128 * 128];
    __shared__ float psL[256], pdL[256];

    int t = threadIdx.x;
    int brow = blockIdx.x * 64;
    int rows = min(64, n - brow);

    // stage X, split hi/lo
    #pragma unroll
    for (int i = 0; i < 8; ++i) {
        int f = t + 256 * i;              // 2048 float4s
        int row = f >> 5, k4 = f & 31;
        float4 v = make_float4(0.f, 0.f, 0.f, 0.f);
        if (row < rows) v = *(const float4*)&x[(size_t)(brow + row) * D + k4 * 4];
        uint h0 = rne16(v.x), h1 = rne16(v.y), h2 = rne16(v.z), h3 = rne16(v.w);
        uint2 ph = make_uint2(h0 | (h1 << 16), h2 | (h3 << 16));
        uint2 pl = make_uint2(bpack(v.x - fromtop(h0), v.y - fromtop(h1)),
                              bpack(v.z - fromtop(h2), v.w - fromtop(h3)));
        int off = row * 256 + k4 * 8;
        int swz = (row & 7) << 4;
        *(uint2*)(XH + (off ^ swz)) = ph;
        *(uint2*)(XL + (off ^ swz)) = pl;
    }

    int wave = t >> 6, lane = t & 63;
    int l15 = lane & 15, lk = lane >> 4;

    f32x4 acc[4][2];
    #pragma unroll
    for (int rt = 0; rt < 4; ++rt)
        #pragma unroll
        for (int ct = 0; ct < 2; ++ct)
            acc[rt][ct] = (f32x4){0.f, 0.f, 0.f, 0.f};

    for (int kc = 0; kc < 2; ++kc) {
        __syncthreads();
        // stage Wt chunk: k in [kc*64, kc*64+64)
        #pragma unroll
        for (int i = 0; i < 4; ++i) {
            int f = t + 256 * i;          // 1024 uint4s
            int col = f >> 3, j = f & 7;
            uint4 vh = *(const uint4*)&wthi[col * 64 + kc * 32 + j * 4];
            uint4 vl = *(const uint4*)&wtlo[col * 64 + kc * 32 + j * 4];
            int off = col * 128 + j * 16;
            int swz = (col & 7) << 4;
            *(uint4*)(WH + (off ^ swz)) = vh;
            *(uint4*)(WL + (off ^ swz)) = vl;
        }
        __syncthreads();
        #pragma unroll
        for (int ks = 0; ks < 2; ++ks) {
            s16x8 ah[4], al[4], bh[2], bl[2];
            #pragma unroll
            for (int rt = 0; rt < 4; ++rt) {
                int row = rt * 16 + l15;
                int off = row * 256 + (kc * 64 + ks * 32 + lk * 8) * 2;
                int swz = (row & 7) << 4;
                ah[rt] = *(const s16x8*)(XH + (off ^ swz));
                al[rt] = *(const s16x8*)(XL + (off ^ swz));
            }
            #pragma unroll
            for (int ct = 0; ct < 2; ++ct) {
                int col = wave * 32 + ct * 16 + l15;
                int off = col * 128 + (ks * 32 + lk * 8) * 2;
                int swz = (col & 7) << 4;
                bh[ct] = *(const s16x8*)(WH + (off ^ swz));
                bl[ct] = *(const s16x8*)(WL + (off ^ swz));
            }
            #pragma unroll
            for (int rt = 0; rt < 4; ++rt)
                #pragma unroll
                for (int ct = 0; ct < 2; ++ct) {
                    acc[rt][ct] = __builtin_amdgcn_mfma_f32_16x16x32_bf16(ah[rt], bh[ct], acc[rt][ct], 0, 0, 0);
                    acc[rt][ct] = __builtin_amdgcn_mfma_f32_16x16x32_bf16(ah[rt], bl[ct], acc[rt][ct], 0, 0, 0);
                    acc[rt][ct] = __builtin_amdgcn_mfma_f32_16x16x32_bf16(al[rt], bh[ct], acc[rt][ct], 0, 0, 0);
                }
        }
    }

    // epilogue: a_src/a_dst partials (this wave's 32 cols), reduce over l15
    float avs_lo = avs[wave * 32 + l15], avs_hi = avs[wave * 32 + 16 + l15];
    float avd_lo = avd[wave * 32 + l15], avd_hi = avd[wave * 32 + 16 + l15];
    #pragma unroll
    for (int rt = 0; rt < 4; ++rt) {
        #pragma unroll
        for (int j = 0; j < 4; ++j) {
            float ps = acc[rt][0][j] * avs_lo + acc[rt][1][j] * avs_hi;
            float pd = acc[rt][0][j] * avd_lo + acc[rt][1][j] * avd_hi;
            #pragma unroll
            for (int off = 8; off; off >>= 1) {
                ps += __shfl_xor(ps, off);
                pd += __shfl_xor(pd, off);
            }
            int row = rt * 16 + lk * 4 + j;
            if (l15 == 0) { psL[wave * 64 + row] = ps; pdL[wave * 64 + row] = pd; }
        }
    }
    // hb store: packed (col, col+16) pairs
    #pragma unroll
    for (int rt = 0; rt < 4; ++rt) {
        #pragma unroll
        for (int j = 0; j < 4; ++j) {
            int row = rt * 16 + lk * 4 + j;
            if (row < rows)
                hb[(size_t)(brow + row) * 64 + wave * 16 + l15] =
                    bpack(acc[rt][0][j], acc[rt][1][j]);
        }
    }
    __syncthreads();
    if (t < 64 && t < rows) {
        asrc[brow + t] = psL[t] + psL[64 + t] + psL[128 + t] + psL[192 + t];
        adst[brow + t] = pdL[t] + pdL[64 + t] + pdL[128 + t] + pdL[192 + t];
    }
}

// ---------------- fused: edge softmax + aggregate (bf16 gather) + residual + LN ----------------
__global__ __launch_bounds__(256) void k_attn(const float* __restrict__ x,
        const uint* __restrict__ hb, const float* __restrict__ asrc,
        const float* __restrict__ adst, const int* __restrict__ rowptr,
        const int* __restrict__ csr, const float* __restrict__ bias,
        const float* __restrict__ gamma, const float* __restrict__ beta,
        float* __restrict__ out, int n) {
    int node = blockIdx.x * 4 + (threadIdx.x >> 6);
    if (node >= n) return;
    int lane = threadIdx.x & 63;
    int grp = lane >> 4;          // 4 edge-groups
    int sl = lane & 15;
    // uint p (=sl*4+i) holds channels (base_lo+i, base_lo+16+i)
    int base_lo = (sl >> 2) * 32 + (sl & 3) * 4;

    float a_i = adst[node];
    float slg = leaky(asrc[node] + a_i);
    int rs = rowptr[node], re = rowptr[node + 1];

    float m = slg;
    for (int e = rs + lane; e < re; e += 64)
        m = fmaxf(m, leaky(asrc[csr[e]] + a_i));
    #pragma unroll
    for (int off = 32; off; off >>= 1) m = fmaxf(m, __shfl_xor(m, off));

    float acc[8] = {0.f, 0.f, 0.f, 0.f, 0.f, 0.f, 0.f, 0.f};
    float ssum = 0.f;
    for (int e = rs; e < re; e += 4) {
        int ee = e + grp;
        if (ee < re) {
            int s = csr[ee];
            float w = __expf(leaky(asrc[s] + a_i) - m);
            ssum += w;
            uint4 q = *(const uint4*)&hb[(size_t)s * 64 + sl * 4];
            acc[0] += w * blo(q.x); acc[1] += w * blo(q.y);
            acc[2] += w * blo(q.z); acc[3] += w * blo(q.w);
            acc[4] += w * bhi(q.x); acc[5] += w * bhi(q.y);
            acc[6] += w * bhi(q.z); acc[7] += w * bhi(q.w);
        }
    }
    if (grp == 0) {  // self loop
        float w = __expf(slg - m);
        ssum += w;
        uint4 q = *(const uint4*)&hb[(size_t)node * 64 + sl * 4];
        acc[0] += w * blo(q.x); acc[1] += w * blo(q.y);
        acc[2] += w * blo(q.z); acc[3] += w * blo(q.w);
        acc[4] += w * bhi(q.x); acc[5] += w * bhi(q.y);
        acc[6] += w * bhi(q.z); acc[7] += w * bhi(q.w);
    }
    #pragma unroll
    for (int off = 16; off <= 32; off <<= 1) {
        ssum += __shfl_xor(ssum, off);
        #pragma unroll
        for (int j = 0; j < 8; ++j) acc[j] += __shfl_xor(acc[j], off);
    }
    float inv = 1.f / ssum;

    float4 xa = *(const float4*)&x[(size_t)node * D + base_lo];
    float4 xb = *(const float4*)&x[(size_t)node * D + base_lo + 16];
    float4 ba = *(const float4*)&bias[base_lo];
    float4 bb = *(const float4*)&bias[base_lo + 16];
    float y[8];
    y[0] = xa.x + acc[0] * inv + ba.x;
    y[1] = xa.y + acc[1] * inv + ba.y;
    y[2] = xa.z + acc[2] * inv + ba.z;
    y[3] = xa.w + acc[3] * inv + ba.w;
    y[4] = xb.x + acc[4] * inv + bb.x;
    y[5] = xb.y + acc[5] * inv + bb.y;
    y[6] = xb.z + acc[6] * inv + bb.z;
    y[7] = xb.w + acc[7] * inv + bb.w;

    float s1 = 0.f, s2 = 0.f;
    #pragma unroll
    for (int j = 0; j < 8; ++j) { s1 += y[j]; s2 += y[j] * y[j]; }
    #pragma unroll
    for (int off = 1; off <= 8; off <<= 1) {
        s1 += __shfl_xor(s1, off);
        s2 += __shfl_xor(s2, off);
    }
    float mu = s1 * (1.f / D);
    float var = s2 * (1.f / D) - mu * mu;
    float rstd = rsqrtf(var + LN_EPS);

    if (grp == 0) {
        float4 ga = *(const float4*)&gamma[base_lo];
        float4 gb = *(const float4*)&gamma[base_lo + 16];
        float4 bta = *(const float4*)&beta[base_lo];
        float4 btb = *(const float4*)&beta[base_lo + 16];
        float4 o0, o1;
        o0.x = (y[0] - mu) * rstd * ga.x + bta.x;
        o0.y = (y[1] - mu) * rstd * ga.y + bta.y;
        o0.z = (y[2] - mu) * rstd * ga.z + bta.z;
        o0.w = (y[3] - mu) * rstd * ga.w + bta.w;
        o1.x = (y[4] - mu) * rstd * gb.x + btb.x;
        o1.y = (y[5] - mu) * rstd * gb.y + btb.y;
        o1.z = (y[6] - mu) * rstd * gb.z + btb.z;
        o1.w = (y[7] - mu) * rstd * gb.w + btb.w;
        *(float4*)&out[(size_t)node * D + base_lo] = o0;
        *(float4*)&out[(size_t)node * D + base_lo + 16] = o1;
    }
}

extern "C" void kernel_launch(void* const* d_in, const int* in_sizes, int n_in,
                              void* d_out, int out_size, void* d_ws, size_t ws_size,
                              hipStream_t stream) {
    const float* x       = (const float*)d_in[0];
    const int*   ei      = (const int*)d_in[1];
    const float* W       = (const float*)d_in[2];
    const float* att_src = (const float*)d_in[3];
    const float* att_dst = (const float*)d_in[4];
    const float* bias    = (const float*)d_in[5];
    const float* gamma   = (const float*)d_in[6];
    const float* beta    = (const float*)d_in[7];
    float* out = (float*)d_out;

    const int N = in_sizes[0] / D;
    const int E = in_sizes[1] / 2;
    const int L = in_sizes[2] / (D * D);

    char* base = (char*)d_ws;
    size_t off = 0;
    auto alloc = [&](size_t bytes) {
        char* p = base + off;
        off += (bytes + 255) & ~(size_t)255;
        return p;
    };
    uint*  hb     = (uint*)alloc((size_t)N * 64 * 4);
    float* asrc   = (float*)alloc((size_t)N * 4);
    float* adst   = (float*)alloc((size_t)N * 4);
    int*   deg    = (int*)alloc((size_t)N * 4);
    int*   rowptr = (int*)alloc((size_t)(N + 1) * 4);
    int*   rank   = (int*)alloc((size_t)E * 4);
    int*   csr    = (int*)alloc((size_t)E * 4);
    const int nb  = (N + 1023) / 1024;
    int*   bsum   = (int*)alloc((size_t)nb * 4);
    int*   ebsum  = (int*)alloc((size_t)nb * 4);
    uint*  wthi   = (uint*)alloc((size_t)D * 64 * 4);
    uint*  wtlo   = (uint*)alloc((size_t)D * 64 * 4);

    hipMemsetAsync(deg, 0, (size_t)N * 4, stream);
    k_degrank<<<(E + 255) / 256, 256, 0, stream>>>(ei, deg, rank, E);
    k_bsum<<<nb, 256, 0, stream>>>(deg, bsum, N);
    k_scanb<<<1, 256, 0, stream>>>(bsum, ebsum, rowptr + N, nb);
    k_rowptr<<<nb, 256, 0, stream>>>(deg, ebsum, rowptr, N);
    k_fill2<<<(E + 255) / 256, 256, 0, stream>>>(ei, rowptr, rank, csr, E);

    const int nblk_node = (N + 3) / 4;
    for (int l = 0; l < L; ++l) {
        const float* xl = (l == 0) ? x : out;
        k_wt<<<8, 256, 0, stream>>>(W + (size_t)l * D * D, wthi, wtlo);
        k_gemm2<<<(N + 63) / 64, 256, 0, stream>>>(xl, wthi, wtlo,
                                                   att_src + (size_t)l * D,
                                                   att_dst + (size_t)l * D,
                                                   hb, asrc, adst, N);
        k_attn<<<nblk_node, 256, 0, stream>>>(xl, hb, asrc, adst, rowptr, csr,
                                              bias + (size_t)l * D, gamma + (size_t)l * D,
                                              beta + (size_t)l * D, out, N);
    }
}